// Round 6
// baseline (260.335 us; speedup 1.0000x reference)
//
#include <hip/hip_runtime.h>
#include <math.h>

#define W 128
#define NANG 128
#define SZ 128
#define NV 8
#define NROWS 2048          // B*C*H
#define K_DIM 1024          // NV * W
#define NPIX 16384          // SZ * SZ
#define OUT_SCALE 0.012271846303085130f   // pi / 256

typedef _Float16 f16x8 __attribute__((ext_vector_type(8)));
typedef _Float16 f16x4 __attribute__((ext_vector_type(4)));
typedef float    f32x4 __attribute__((ext_vector_type(4)));

// ws layout:
//   [36864, +4MiB)  : Pf  f16 [2048 r][8 v][128 t]
//   [.., +32MiB)    : Wv  f16 [16384 pix][1024 k]
#define PF_OFF 36864
#define WV_OFF (36864 + (size_t)NROWS * K_DIM * 2)

struct Ptrs8 { const float* p[8]; };

__device__ __forceinline__ void glds16(const void* g, void* l) {
    __builtin_amdgcn_global_load_lds(
        (const __attribute__((address_space(1))) void*)g,
        (__attribute__((address_space(3))) void*)l, 16, 0, 0);
}

// ---- kernel 1: fused prep ----
// blocks [0,256): filter-GEMM  Pf[(r,v)][t] = sum_s In[v][r][s] * C[t][s]
//   with the circulant C built in LDS from locally-computed filter taps.
// blocks [256,2304): Wv[pixel][k] fused angle-lerp x detector-lerp weights,
//   with the cos/sin table computed locally.
#define FS_A 136   // padded LDS row stride (halfs): +8 -> 2-way bank alias only
#define PREP_FG_BLOCKS 256

union PrepLds {
    struct {                        // fgemm role (52.7 KB)
        _Float16 sA[64 * FS_A];
        _Float16 sB[128 * FS_A];
        float    kl[W];
    } fg;
    struct {                        // wv role (33.8 KB)
        float  wrow[8 * K_DIM];
        float2 cst[NANG];
    } wv;
};

__global__ __launch_bounds__(256)
void k_prep(Ptrs8 in, _Float16* __restrict__ pf, _Float16* __restrict__ wv) {
    __shared__ PrepLds u;
    const int tid = threadIdx.x;

    if (blockIdx.x < PREP_FG_BLOCKS) {
        // ================= filter-GEMM role =================
        const int blk  = blockIdx.x;
        const int lane = tid & 63, wave = tid >> 6;
        const int fr = lane & 15, fg = lane >> 4;

        if (tid < W) {
            const int d = tid;
            const float w0 = 6.283185307179586f / (float)W * (float)d;
            float s = 0.f;
            for (int f = 1; f < 64; ++f)
                s = fmaf((float)f, __cosf(w0 * (float)f), s);
            s = 2.f * s + 64.f * ((d & 1) ? -1.f : 1.f);
            u.fg.kl[d] = s * (1.f / (float)(W * W));
        }
        {
            const int i   = tid >> 5;          // row-within-view-group 0..7
            const int pos = (tid & 31) * 4;    // f32 position 0..124
#pragma unroll
            for (int v = 0; v < NV; ++v) {
                float4 x = *(const float4*)(in.p[v] + (size_t)(blk * 8 + i) * W + pos);
                f16x4 h = { (_Float16)x.x, (_Float16)x.y, (_Float16)x.z, (_Float16)x.w };
                *(f16x4*)&u.fg.sA[(i * 8 + v) * FS_A + pos] = h;
            }
        }
        __syncthreads();
        for (int e = tid; e < W * W; e += 256) {
            const int t = e >> 7, s = e & 127;
            u.fg.sB[t * FS_A + s] = (_Float16)u.fg.kl[(t - s) & (W - 1)];
        }
        __syncthreads();

        f32x4 acc[8] = {};
#pragma unroll
        for (int kb = 0; kb < W; kb += 32) {
            f16x8 af = *(const f16x8*)&u.fg.sA[(wave * 16 + fr) * FS_A + kb + fg * 8];
#pragma unroll
            for (int nt = 0; nt < 8; ++nt) {
                f16x8 bf = *(const f16x8*)&u.fg.sB[(nt * 16 + fr) * FS_A + kb + fg * 8];
                acc[nt] = __builtin_amdgcn_mfma_f32_16x16x32_f16(af, bf, acc[nt], 0, 0, 0);
            }
        }
#pragma unroll
        for (int nt = 0; nt < 8; ++nt) {
            int m = blk * 64 + wave * 16 + fg * 4;
            int n = nt * 16 + fr;
#pragma unroll
            for (int rr = 0; rr < 4; ++rr)
                pf[(size_t)(m + rr) * W + n] = (_Float16)acc[nt][rr];
        }
    } else {
        // ================= Wv role =================
        const int p0 = (blockIdx.x - PREP_FG_BLOCKS) * 8;
        if (tid < NANG) {
            float th = (float)tid * ((float)M_PI / (float)NANG);
            u.wv.cst[tid] = make_float2(cosf(th), sinf(th));
        }
        for (int i = tid; i < 8 * K_DIM; i += 256) u.wv.wrow[i] = 0.f;
        __syncthreads();
        const int px  = tid >> 5;
        const int sub = tid & 31;
        const int p = p0 + px;
        const float x = (float)(p & 127) - 63.5f;
        const float y = (float)(p >> 7) - 63.5f;
        float* prow = &u.wv.wrow[px * K_DIM];
        for (int a = sub; a < NANG; a += 32) {
            float2 c = u.wv.cst[a];
            float t = fmaf(x, c.x, fmaf(y, c.y, 63.5f));
            t = fminf(fmaxf(t, 0.f), 127.f);
            float tf = fminf(floorf(t), 126.f);
            int   ti = (int)tf;
            float wt = t - tf;
            float src = ((float)a + 0.5f) * 0.0625f - 0.5f;
            src = fminf(fmaxf(src, 0.f), 7.f);
            float vf = floorf(src);
            int   v0 = (int)vf;
            int   v1 = v0 + 1 < NV ? v0 + 1 : NV - 1;
            float wa = src - vf;
            float wA0 = (1.f - wa) * OUT_SCALE;
            atomicAdd(&prow[v0 * W + ti],     wA0 * (1.f - wt));
            atomicAdd(&prow[v0 * W + ti + 1], wA0 * wt);
            if (v1 != v0) {
                float wA1 = wa * OUT_SCALE;
                atomicAdd(&prow[v1 * W + ti],     wA1 * (1.f - wt));
                atomicAdd(&prow[v1 * W + ti + 1], wA1 * wt);
            }
        }
        __syncthreads();
        uint* wvu = (uint*)(wv + (size_t)p0 * K_DIM);
#pragma unroll
        for (int j = 0; j < 16; ++j) {
            int j2 = tid + 256 * j;
            float2 w2 = *(const float2*)&u.wv.wrow[j2 * 2];
            union { uint uu; struct { _Float16 lo, hi; } h; } pk;
            pk.h.lo = (_Float16)w2.x; pk.h.hi = (_Float16)w2.y;
            wvu[j2] = pk.uu;
        }
    }
}

// ---- kernel 2: 128x128-tile GEMM, 4 blocks/CU for cross-block overlap ----
// Out[m][n] = sum_k Pf[m][k] * Wv[n][k].  M=2048, N=16384, K=1024.
// 256 threads = 4 waves (2M x 2N), per-wave 64x64 output -> acc = 64 VGPR,
// total <=128/thread -> 16-waves/CU occupancy bucket.  LDS 32 KiB
// (double-buffered A[128][32] + B[128][32]) -> 4 blocks/CU.  Independent
// blocks have no shared barrier: when one block drains at its tile-end
// barrier, the other three feed the MFMA/LDS pipes (m114 co-scheduling) --
// the overlap our 1-block/CU 256^2 kernel could not get (r4/r5 nulls).
// Per K-tile (BK=32): stage next tile into other buffer (4 glds16), 8
// ds_read_b128, 16 MFMA, lgkmcnt(0)+vmcnt(0), one barrier.
#define NT3 32   // K_DIM / 32

__device__ __forceinline__ void fencebar() {
    asm volatile("" ::: "memory");
    __builtin_amdgcn_s_barrier();
    asm volatile("" ::: "memory");
}

// Stage one 128x32-half (8 KiB) panel of G (row-major [rows][K_DIM]) into
// LDS region L (linear), K columns kt*32..+31.  2 glds16/thread (256 thr).
// Global source inverse-swizzled so reads apply q ^= row&3; LDS dest linear.
__device__ __forceinline__ void stage3(const _Float16* __restrict__ G, int R0,
                                       int kt, _Float16* L, int tid) {
#pragma unroll
    for (int r = 0; r < 2; ++r) {
        const int c   = r * 256 + tid;            // chunk 0..511 (16 B each)
        const int row = c >> 2;                   // 0..127
        const int q   = c & 3;
        const _Float16* src = G + (size_t)(R0 + row) * K_DIM + kt * 32
                                + ((q ^ (row & 3)) << 3);
        _Float16* dst = L + ((r * 256 + (tid & 192)) << 3);   // wave-uniform base
        glds16(src, dst);
    }
}

__device__ __forceinline__ f16x8 frag3(const _Float16* L, int row, int q) {
    return *(const f16x8*)(L + row * 32 + ((q ^ (row & 3)) << 3));
}

__global__ __launch_bounds__(256, 4)
void k_gemm(const _Float16* __restrict__ A,
            const _Float16* __restrict__ Bm,
            float* __restrict__ out) {
    __shared__ _Float16 lds[16384];   // 32 KiB
    const int tid  = threadIdx.x;
    const int lane = tid & 63, wid = tid >> 6;
    const int wm = wid >> 1, wn = wid & 1;
    const int fr = lane & 15, fg = lane >> 4;

    // bijective XCD swizzle (2048 blocks % 8 == 0): XCD x owns n-tiles
    // [x*16, x*16+16) across all 16 m-tiles.
    const int flat = blockIdx.x;
    const int x    = flat & 7;
    const int idx  = flat >> 3;            // 0..255
    const int m0 = (idx & 15) * 128;
    const int n0 = (x * 16 + (idx >> 4)) * 128;

    _Float16* const A0 = lds;
    _Float16* const B0 = lds + 4096;
    _Float16* const A1 = lds + 8192;
    _Float16* const B1 = lds + 12288;

    // prologue: tile 0 (depth-1 pipeline; other resident blocks cover the fill)
    stage3(A,  m0, 0, A0, tid);
    stage3(Bm, n0, 0, B0, tid);
    asm volatile("s_waitcnt vmcnt(0)" ::: "memory");
    fencebar();

    f32x4 acc[4][4] = {};
    f16x8 af[4], bf[4];
    const int ar = wm * 64 + fr;
    const int br = wn * 64 + fr;

    auto tile = [&](int t, _Float16* Ab, _Float16* Bb, _Float16* An, _Float16* Bn)
        __attribute__((always_inline)) {
        if (t + 1 < NT3) {
            stage3(A,  m0, t + 1, An, tid);
            stage3(Bm, n0, t + 1, Bn, tid);
        }
#pragma unroll
        for (int i = 0; i < 4; ++i) af[i] = frag3(Ab, ar + i * 16, fg);
#pragma unroll
        for (int j = 0; j < 4; ++j) bf[j] = frag3(Bb, br + j * 16, fg);
        __builtin_amdgcn_s_setprio(1);
#pragma unroll
        for (int i = 0; i < 4; ++i)
#pragma unroll
            for (int j = 0; j < 4; ++j)
                acc[i][j] = __builtin_amdgcn_mfma_f32_16x16x32_f16(
                    af[i], bf[j], acc[i][j], 0, 0, 0);
        __builtin_amdgcn_s_setprio(0);
        asm volatile("s_waitcnt lgkmcnt(0)" ::: "memory");  // my reads of Ab/Bb done
        if (t + 1 < NT3)
            asm volatile("s_waitcnt vmcnt(0)" ::: "memory"); // next-tile stage landed
        fencebar();
    };

    for (int tt = 0; tt < NT3; tt += 2) {
        tile(tt,     A0, B0, A1, B1);
        tile(tt + 1, A1, B1, A0, B0);
    }

    // epilogue: C/D col = fr (n), row = fg*4 + rr (m within 16)
#pragma unroll
    for (int i = 0; i < 4; ++i) {
#pragma unroll
        for (int j = 0; j < 4; ++j) {
            const int m = m0 + wm * 64 + i * 16 + fg * 4;
            const int n = n0 + wn * 64 + j * 16 + fr;
            float* op = out + (size_t)m * NPIX + n;
#pragma unroll
            for (int rr = 0; rr < 4; ++rr)
                op[(size_t)rr * NPIX] = acc[i][j][rr];
        }
    }
}

extern "C" void kernel_launch(void* const* d_in, const int* in_sizes, int n_in,
                              void* d_out, int out_size, void* d_ws, size_t ws_size,
                              hipStream_t stream) {
    _Float16*   pf = (_Float16*)((char*)d_ws + PF_OFF);
    _Float16*   wv = (_Float16*)((char*)d_ws + WV_OFF);

    Ptrs8 in;
    for (int i = 0; i < NV; ++i) in.p[i] = (const float*)d_in[i];

    k_prep<<<PREP_FG_BLOCKS + NPIX / 8, 256, 0, stream>>>(in, pf, wv);
    k_gemm<<<(NROWS / 128) * (NPIX / 128), 256, 0, stream>>>(pf, wv, (float*)d_out);
}

// Round 7
// 259.787 us; speedup vs baseline: 1.0021x; 1.0021x over previous
//
#include <hip/hip_runtime.h>
#include <math.h>

#define W 128
#define NANG 128
#define SZ 128
#define NV 8
#define NROWS 2048          // B*C*H
#define K_DIM 1024          // NV * W
#define NPIX 16384          // SZ * SZ
#define OUT_SCALE 0.012271846303085130f   // pi / 256

typedef _Float16 f16x8 __attribute__((ext_vector_type(8)));
typedef _Float16 f16x4 __attribute__((ext_vector_type(4)));
typedef float    f32x4 __attribute__((ext_vector_type(4)));

// ws layout:
//   [36864, +4MiB)  : Pf  f16 [2048 r][8 v][128 t]
//   [.., +32MiB)    : Wv  f16 [16384 pix][1024 k]
#define PF_OFF 36864
#define WV_OFF (36864 + (size_t)NROWS * K_DIM * 2)

struct Ptrs8 { const float* p[8]; };

__device__ __forceinline__ void glds16(const void* g, void* l) {
    __builtin_amdgcn_global_load_lds(
        (const __attribute__((address_space(1))) void*)g,
        (__attribute__((address_space(3))) void*)l, 16, 0, 0);
}

// ---- kernel 1: fused prep ----
// blocks [0,256): filter-GEMM  Pf[(r,v)][t] = sum_s In[v][r][s] * C[t][s]
//   with the circulant C built in LDS from locally-computed filter taps.
// blocks [256,2304): Wv[pixel][k] fused angle-lerp x detector-lerp weights,
//   with the cos/sin table computed locally.
#define FS_A 136   // padded LDS row stride (halfs): +8 -> 2-way bank alias only
#define PREP_FG_BLOCKS 256

union PrepLds {
    struct {                        // fgemm role (52.7 KB)
        _Float16 sA[64 * FS_A];
        _Float16 sB[128 * FS_A];
        float    kl[W];
    } fg;
    struct {                        // wv role (33.8 KB)
        float  wrow[8 * K_DIM];
        float2 cst[NANG];
    } wv;
};

__global__ __launch_bounds__(256)
void k_prep(Ptrs8 in, _Float16* __restrict__ pf, _Float16* __restrict__ wv) {
    __shared__ PrepLds u;
    const int tid = threadIdx.x;

    if (blockIdx.x < PREP_FG_BLOCKS) {
        // ================= filter-GEMM role =================
        const int blk  = blockIdx.x;
        const int lane = tid & 63, wave = tid >> 6;
        const int fr = lane & 15, fg = lane >> 4;

        if (tid < W) {
            const int d = tid;
            const float w0 = 6.283185307179586f / (float)W * (float)d;
            float s = 0.f;
            for (int f = 1; f < 64; ++f)
                s = fmaf((float)f, __cosf(w0 * (float)f), s);
            s = 2.f * s + 64.f * ((d & 1) ? -1.f : 1.f);
            u.fg.kl[d] = s * (1.f / (float)(W * W));
        }
        {
            const int i   = tid >> 5;          // row-within-view-group 0..7
            const int pos = (tid & 31) * 4;    // f32 position 0..124
#pragma unroll
            for (int v = 0; v < NV; ++v) {
                float4 x = *(const float4*)(in.p[v] + (size_t)(blk * 8 + i) * W + pos);
                f16x4 h = { (_Float16)x.x, (_Float16)x.y, (_Float16)x.z, (_Float16)x.w };
                *(f16x4*)&u.fg.sA[(i * 8 + v) * FS_A + pos] = h;
            }
        }
        __syncthreads();
        for (int e = tid; e < W * W; e += 256) {
            const int t = e >> 7, s = e & 127;
            u.fg.sB[t * FS_A + s] = (_Float16)u.fg.kl[(t - s) & (W - 1)];
        }
        __syncthreads();

        f32x4 acc[8] = {};
#pragma unroll
        for (int kb = 0; kb < W; kb += 32) {
            f16x8 af = *(const f16x8*)&u.fg.sA[(wave * 16 + fr) * FS_A + kb + fg * 8];
#pragma unroll
            for (int nt = 0; nt < 8; ++nt) {
                f16x8 bf = *(const f16x8*)&u.fg.sB[(nt * 16 + fr) * FS_A + kb + fg * 8];
                acc[nt] = __builtin_amdgcn_mfma_f32_16x16x32_f16(af, bf, acc[nt], 0, 0, 0);
            }
        }
#pragma unroll
        for (int nt = 0; nt < 8; ++nt) {
            int m = blk * 64 + wave * 16 + fg * 4;
            int n = nt * 16 + fr;
#pragma unroll
            for (int rr = 0; rr < 4; ++rr)
                pf[(size_t)(m + rr) * W + n] = (_Float16)acc[nt][rr];
        }
    } else {
        // ================= Wv role =================
        const int p0 = (blockIdx.x - PREP_FG_BLOCKS) * 8;
        if (tid < NANG) {
            float th = (float)tid * ((float)M_PI / (float)NANG);
            u.wv.cst[tid] = make_float2(cosf(th), sinf(th));
        }
        for (int i = tid; i < 8 * K_DIM; i += 256) u.wv.wrow[i] = 0.f;
        __syncthreads();
        const int px  = tid >> 5;
        const int sub = tid & 31;
        const int p = p0 + px;
        const float x = (float)(p & 127) - 63.5f;
        const float y = (float)(p >> 7) - 63.5f;
        float* prow = &u.wv.wrow[px * K_DIM];
        for (int a = sub; a < NANG; a += 32) {
            float2 c = u.wv.cst[a];
            float t = fmaf(x, c.x, fmaf(y, c.y, 63.5f));
            t = fminf(fmaxf(t, 0.f), 127.f);
            float tf = fminf(floorf(t), 126.f);
            int   ti = (int)tf;
            float wt = t - tf;
            float src = ((float)a + 0.5f) * 0.0625f - 0.5f;
            src = fminf(fmaxf(src, 0.f), 7.f);
            float vf = floorf(src);
            int   v0 = (int)vf;
            int   v1 = v0 + 1 < NV ? v0 + 1 : NV - 1;
            float wa = src - vf;
            float wA0 = (1.f - wa) * OUT_SCALE;
            atomicAdd(&prow[v0 * W + ti],     wA0 * (1.f - wt));
            atomicAdd(&prow[v0 * W + ti + 1], wA0 * wt);
            if (v1 != v0) {
                float wA1 = wa * OUT_SCALE;
                atomicAdd(&prow[v1 * W + ti],     wA1 * (1.f - wt));
                atomicAdd(&prow[v1 * W + ti + 1], wA1 * wt);
            }
        }
        __syncthreads();
        uint* wvu = (uint*)(wv + (size_t)p0 * K_DIM);
#pragma unroll
        for (int j = 0; j < 16; ++j) {
            int j2 = tid + 256 * j;
            float2 w2 = *(const float2*)&u.wv.wrow[j2 * 2];
            union { uint uu; struct { _Float16 lo, hi; } h; } pk;
            pk.h.lo = (_Float16)w2.x; pk.h.hi = (_Float16)w2.y;
            wvu[j2] = pk.uu;
        }
    }
}

// ---- kernel 2: 128x128-tile GEMM, 4 blocks/CU, FIXED bank swizzle ----
// Out[m][n] = sum_k Pf[m][k] * Wv[n][k].  M=2048, N=16384, K=1024.
// 256 threads = 4 waves (2M x 2N), per-wave 64x64 output, acc = 64 VGPR,
// 32 KiB LDS -> 4 blocks/CU (cross-block MFMA/LDS overlap, r6 confirmed
// occupancy 36%).  r6 BUG: swizzle q^(row&3) collided rows r,r+4 within an
// 8-lane read phase (row stride 64 B = HALF a bank wrap, so row&1 already
// enters the bank base) -> 2-way conflict on every ds_read_b128 (8.4M
// counter, 2x LDS time).  FIX: swizzle on the row bits NOT in the bank base:
// q ^= (row>>1)&3.  bank = 16*(row&1) + 4*(q^((row>>1)&3)): rows r0..r0+7 at
// fixed q hit all 8 distinct bank quads -> conflict-free.
#define NT3 32   // K_DIM / 32

__device__ __forceinline__ void fencebar() {
    asm volatile("" ::: "memory");
    __builtin_amdgcn_s_barrier();
    asm volatile("" ::: "memory");
}

// Stage one 128x32-half (8 KiB) panel of G (row-major [rows][K_DIM]) into
// LDS region L (linear), K columns kt*32..+31.  2 glds16/thread (256 thr).
// Global source inverse-swizzled (involution) so reads apply the same XOR.
__device__ __forceinline__ void stage3(const _Float16* __restrict__ G, int R0,
                                       int kt, _Float16* L, int tid) {
#pragma unroll
    for (int r = 0; r < 2; ++r) {
        const int c   = r * 256 + tid;            // chunk 0..511 (16 B each)
        const int row = c >> 2;                   // 0..127
        const int q   = c & 3;
        const _Float16* src = G + (size_t)(R0 + row) * K_DIM + kt * 32
                                + ((q ^ ((row >> 1) & 3)) << 3);
        _Float16* dst = L + ((r * 256 + (tid & 192)) << 3);   // wave-uniform base
        glds16(src, dst);
    }
}

__device__ __forceinline__ f16x8 frag3(const _Float16* L, int row, int q) {
    return *(const f16x8*)(L + row * 32 + ((q ^ ((row >> 1) & 3)) << 3));
}

__global__ __launch_bounds__(256, 4)
void k_gemm(const _Float16* __restrict__ A,
            const _Float16* __restrict__ Bm,
            float* __restrict__ out) {
    __shared__ _Float16 lds[16384];   // 32 KiB
    const int tid  = threadIdx.x;
    const int lane = tid & 63, wid = tid >> 6;
    const int wm = wid >> 1, wn = wid & 1;
    const int fr = lane & 15, fg = lane >> 4;

    // bijective XCD swizzle (2048 blocks % 8 == 0): XCD x owns n-tiles
    // [x*16, x*16+16) across all 16 m-tiles.
    const int flat = blockIdx.x;
    const int x    = flat & 7;
    const int idx  = flat >> 3;            // 0..255
    const int m0 = (idx & 15) * 128;
    const int n0 = (x * 16 + (idx >> 4)) * 128;

    _Float16* const A0 = lds;
    _Float16* const B0 = lds + 4096;
    _Float16* const A1 = lds + 8192;
    _Float16* const B1 = lds + 12288;

    // prologue: tile 0 (depth-1 pipeline; other resident blocks cover the fill)
    stage3(A,  m0, 0, A0, tid);
    stage3(Bm, n0, 0, B0, tid);
    asm volatile("s_waitcnt vmcnt(0)" ::: "memory");
    fencebar();

    f32x4 acc[4][4] = {};
    f16x8 af[4], bf[4];
    const int ar = wm * 64 + fr;
    const int br = wn * 64 + fr;

    auto tile = [&](int t, _Float16* Ab, _Float16* Bb, _Float16* An, _Float16* Bn)
        __attribute__((always_inline)) {
        if (t + 1 < NT3) {
            stage3(A,  m0, t + 1, An, tid);
            stage3(Bm, n0, t + 1, Bn, tid);
        }
#pragma unroll
        for (int i = 0; i < 4; ++i) af[i] = frag3(Ab, ar + i * 16, fg);
#pragma unroll
        for (int j = 0; j < 4; ++j) bf[j] = frag3(Bb, br + j * 16, fg);
        __builtin_amdgcn_s_setprio(1);
#pragma unroll
        for (int i = 0; i < 4; ++i)
#pragma unroll
            for (int j = 0; j < 4; ++j)
                acc[i][j] = __builtin_amdgcn_mfma_f32_16x16x32_f16(
                    af[i], bf[j], acc[i][j], 0, 0, 0);
        __builtin_amdgcn_s_setprio(0);
        asm volatile("s_waitcnt lgkmcnt(0)" ::: "memory");  // my reads of Ab/Bb done
        if (t + 1 < NT3)
            asm volatile("s_waitcnt vmcnt(0)" ::: "memory"); // next-tile stage landed
        fencebar();
    };

    for (int tt = 0; tt < NT3; tt += 2) {
        tile(tt,     A0, B0, A1, B1);
        tile(tt + 1, A1, B1, A0, B0);
    }

    // epilogue: C/D col = fr (n), row = fg*4 + rr (m within 16)
#pragma unroll
    for (int i = 0; i < 4; ++i) {
#pragma unroll
        for (int j = 0; j < 4; ++j) {
            const int m = m0 + wm * 64 + i * 16 + fg * 4;
            const int n = n0 + wn * 64 + j * 16 + fr;
            float* op = out + (size_t)m * NPIX + n;
#pragma unroll
            for (int rr = 0; rr < 4; ++rr)
                op[(size_t)rr * NPIX] = acc[i][j][rr];
        }
    }
}

extern "C" void kernel_launch(void* const* d_in, const int* in_sizes, int n_in,
                              void* d_out, int out_size, void* d_ws, size_t ws_size,
                              hipStream_t stream) {
    _Float16*   pf = (_Float16*)((char*)d_ws + PF_OFF);
    _Float16*   wv = (_Float16*)((char*)d_ws + WV_OFF);

    Ptrs8 in;
    for (int i = 0; i < NV; ++i) in.p[i] = (const float*)d_in[i];

    k_prep<<<PREP_FG_BLOCKS + NPIX / 8, 256, 0, stream>>>(in, pf, wv);
    k_gemm<<<(NROWS / 128) * (NPIX / 128), 256, 0, stream>>>(pf, wv, (float*)d_out);
}